// Round 1
// baseline (886.601 us; speedup 1.0000x reference)
//
#include <hip/hip_runtime.h>
#include <stdint.h>

#define B_ 8
#define D_ 512
#define N_ 16384
#define K_ 32
#define TN_ 64
#define NCHUNK_ 512
#define NTILES_ 8
#define NBLOCKS_ (B_ * 32)

// ---- bf16 pair helpers (RNE pack, shift unpack) ----
__device__ __forceinline__ uint32_t bfpack2(float lo, float hi) {
    uint32_t a = __float_as_uint(lo);
    uint32_t b = __float_as_uint(hi);
    a += 0x7FFFu + ((a >> 16) & 1u);
    b += 0x7FFFu + ((b >> 16) & 1u);
    return (a >> 16) | (b & 0xFFFF0000u);
}
__device__ __forceinline__ float bflo(uint32_t v) { return __uint_as_float(v << 16); }
__device__ __forceinline__ float bfhi(uint32_t v) { return __uint_as_float(v & 0xFFFF0000u); }

// XOR-swizzled LDS tile index: element (n, p) of a [64][256] uint32 grid.
// Conflict-free for column access (fixed p, lanes vary n) and <=2-way for
// row access (fixed n, lanes vary p).
#define XIDX(n, p) (((n) << 8) | ((p) ^ ((n) & 31)))

__launch_bounds__(512, 2)
__global__ void encode_kernel(const float* __restrict__ X,
                              const float* __restrict__ Cg,
                              const float* __restrict__ scale,
                              float* __restrict__ acc,
                              float* __restrict__ aSumAcc)
{
    // LDS: 65536 + 8448 + 256 + 128 + 128 = 74,496 B  (1 block/CU)
    __shared__ uint32_t xs[TN_ * 256];     // X tile, bf16x2 along d, swizzled
    __shared__ float Axc[TN_][K_ + 1];     // xc partial sums, then A in-place
    __shared__ float x2s[TN_];             // fp32 row norms
    __shared__ float scs[K_];
    __shared__ float c2s[K_];

    const int tid   = threadIdx.x;
    const int bid   = blockIdx.x;
    const int b     = bid >> 5;
    const int chunk = bid & 31;
    const float* Xb = X + (size_t)b * ((size_t)D_ * N_) + chunk * NCHUNK_;

    // per-block constants: scale + ||c_k||^2 (fp32, from global fp32 C)
    if (tid < K_) {
        scs[tid] = scale[tid];
        const float* cr = Cg + tid * D_;
        float s2 = 0.f;
        for (int d = 0; d < D_; d += 4) {
            float4 v = *(const float4*)(cr + d);
            s2 += v.x * v.x + v.y * v.y + v.z * v.z + v.w * v.w;
        }
        c2s[tid] = s2;
    }

    // persistent accumulators
    float ep[8][8];
#pragma unroll
    for (int j = 0; j < 8; ++j)
#pragma unroll
        for (int i = 0; i < 8; ++i) ep[j][i] = 0.f;
    float aSumReg = 0.f;

    // thread mappings
    const int sn    = tid & 63;   // staging: n
    const int strip = tid >> 6;   // staging: 32-wide p strip
    const int wv    = __builtin_amdgcn_readfirstlane(tid >> 6);
    const int lane  = tid & 63;
    const int kb1   = (wv & 3) << 3;  // phase1: k base (wave-uniform -> s_load C)
    const int dg1   = wv >> 2;        // phase1: p half
    const int h3    = tid >> 8;       // phase3: n half
    const int r3    = tid & 255;
    const int kb3   = (r3 & 3) << 3;  // phase3: k base
    const int dsid  = r3 >> 2;        // phase3: d octet id

    for (int t = 0; t < NTILES_; ++t) {
        __syncthreads();  // previous tile fully consumed

        // zero xc accumulators + row norms
        {
            float* az = &Axc[0][0];
            for (int i = tid; i < TN_ * (K_ + 1); i += 512) az[i] = 0.f;
            if (tid < TN_) x2s[tid] = 0.f;
        }

        // ---- stage tile: global fp32 -> fp32 x2 partial + bf16x2 LDS ----
        const float* Xt = Xb + t * TN_;
        float x2p = 0.f;
#pragma unroll 4
        for (int pp = 0; pp < 32; ++pp) {
            int p = (strip << 5) + pp;
            float v0 = Xt[(size_t)(2 * p) * N_ + sn];
            float v1 = Xt[(size_t)(2 * p + 1) * N_ + sn];
            x2p += v0 * v0 + v1 * v1;
            xs[XIDX(sn, p)] = bfpack2(v0, v1);
        }
        __syncthreads();  // barrier A: tile + zeros visible
        unsafeAtomicAdd(&x2s[sn], x2p);

        // ---- phase 1: xc[n][k] partials (wave-uniform k-set & d-half) ----
        {
            float xcp[8];
#pragma unroll
            for (int j = 0; j < 8; ++j) xcp[j] = 0.f;
            const float* C0 = Cg + kb1 * D_;
#pragma unroll 2
            for (int pp = 0; pp < 128; ++pp) {
                int p = (dg1 << 7) + pp;
                uint32_t xv = xs[XIDX(lane, p)];
                float xlo = bflo(xv), xhi = bfhi(xv);
#pragma unroll
                for (int j = 0; j < 8; ++j) {
                    float clo = C0[j * D_ + 2 * p];
                    float chi = C0[j * D_ + 2 * p + 1];
                    xcp[j] = fmaf(xlo, clo, xcp[j]);
                    xcp[j] = fmaf(xhi, chi, xcp[j]);
                }
            }
#pragma unroll
            for (int j = 0; j < 8; ++j)
                unsafeAtomicAdd(&Axc[lane][kb1 + j], xcp[j]);
        }
        __syncthreads();  // barrier B: xc + x2 complete

        // ---- phase 2: softmax over k (wave 0, lane = n), A overwrites xc ----
        if (tid < TN_) {
            const int n = tid;
            float x2v = x2s[n];
            float lg[K_];
            float m = -3.0e38f;
#pragma unroll
            for (int k = 0; k < K_; ++k) {
                float xc = Axc[n][k];
                float sl = scs[k] * (x2v - 2.f * xc + c2s[k]);
                lg[k] = sl;
                m = fmaxf(m, sl);
            }
            float s = 0.f;
#pragma unroll
            for (int k = 0; k < K_; ++k) {
                float e = __expf(lg[k] - m);
                lg[k] = e;
                s += e;
            }
            float inv = 1.f / s;
#pragma unroll
            for (int k = 0; k < K_; ++k) Axc[n][k] = lg[k] * inv;
        }
        __syncthreads();  // barrier C: A ready

        // aSum[k] column sums (threads 0..31; overlaps with phase 3 start)
        if (tid < K_) {
            float s = 0.f;
            for (int n = 0; n < TN_; ++n) s += Axc[n][tid];
            aSumReg += s;
        }

        // ---- phase 3: E[k][d] += sum_n A[n][k] * X[n][d] ----
        for (int nn = 0; nn < 32; ++nn) {
            int n = (h3 << 5) + nn;
            float ar[8];
#pragma unroll
            for (int j = 0; j < 8; ++j) ar[j] = Axc[n][kb3 + j];
            float xf[8];
#pragma unroll
            for (int ii = 0; ii < 4; ++ii) {
                uint32_t v = xs[XIDX(n, (dsid << 2) + ii)];
                xf[2 * ii]     = bflo(v);
                xf[2 * ii + 1] = bfhi(v);
            }
#pragma unroll
            for (int j = 0; j < 8; ++j)
#pragma unroll
                for (int i = 0; i < 8; ++i)
                    ep[j][i] = fmaf(ar[j], xf[i], ep[j][i]);
        }
    }

    // ---- finalize: reduce partials into workspace ----
    float* accB = acc + (size_t)b * (K_ * D_);
#pragma unroll
    for (int j = 0; j < 8; ++j)
#pragma unroll
        for (int i = 0; i < 8; ++i)
            unsafeAtomicAdd(&accB[(kb3 + j) * D_ + (dsid << 3) + i], ep[j][i]);

    if (tid < K_) unsafeAtomicAdd(&aSumAcc[(b << 5) + tid], aSumReg);
}

// out[b,k,d] = acc[b,k,d] - aSum[b,k] * C[k,d]
__global__ void finish_kernel(const float* __restrict__ acc,
                              const float* __restrict__ aSumAcc,
                              const float* __restrict__ Cg,
                              float* __restrict__ out)
{
    int idx = blockIdx.x * 256 + threadIdx.x;
    int kd = idx & (K_ * D_ - 1);
    int b  = idx >> 14;
    int k  = kd >> 9;
    out[idx] = acc[idx] - aSumAcc[(b << 5) + k] * Cg[kd];
}

extern "C" void kernel_launch(void* const* d_in, const int* in_sizes, int n_in,
                              void* d_out, int out_size, void* d_ws, size_t ws_size,
                              hipStream_t stream)
{
    const float* X  = (const float*)d_in[0];
    const float* C  = (const float*)d_in[1];
    const float* sc = (const float*)d_in[2];
    float* out = (float*)d_out;

    float* acc      = (float*)d_ws;           // B*K*D fp32 partial E
    float* aSumAcc  = acc + B_ * K_ * D_;     // B*K   fp32 sum of A

    hipMemsetAsync(d_ws, 0, (size_t)(B_ * K_ * D_ + B_ * K_) * sizeof(float), stream);
    encode_kernel<<<NBLOCKS_, 512, 0, stream>>>(X, C, sc, acc, aSumAcc);
    finish_kernel<<<(B_ * K_ * D_) / 256, 256, 0, stream>>>(acc, aSumAcc, C, out);
}

// Round 2
// 392.863 us; speedup vs baseline: 2.2568x; 2.2568x over previous
//
#include <hip/hip_runtime.h>
#include <stdint.h>

#define B_ 8
#define D_ 512
#define N_ 16384
#define K_ 32

typedef __attribute__((ext_vector_type(8))) short short8;
typedef __attribute__((ext_vector_type(16))) float f32x16;

union F8 { short8 v; unsigned short s[8]; uint32_t u[4]; uint4 q; };

// RNE pack of two fp32 -> bf16x2 in one u32
__device__ __forceinline__ uint32_t bfpack2(float lo, float hi) {
    uint32_t a = __float_as_uint(lo);
    uint32_t b = __float_as_uint(hi);
    a += 0x7FFFu + ((a >> 16) & 1u);
    b += 0x7FFFu + ((b >> 16) & 1u);
    return (a >> 16) | (b & 0xFFFF0000u);
}

// Per block: 32 n-rows x 512 d, tile in LDS as bf16 [d][n] rows padded to 40 u16
// (pad keeps b128 reads 16B-aligned and spreads banks; 20*word stride).
__launch_bounds__(256, 2)
__global__ void encode_kernel(const float* __restrict__ X,
                              const float* __restrict__ Cg,
                              const float* __restrict__ scale,
                              float* __restrict__ acc,
                              float* __restrict__ aSumAcc)
{
    __shared__ uint32_t xsTw[D_ * 20];     // 40960 B: X^T tile bf16, row stride 40 u16
    __shared__ float    lgp[4][32][33];    // 16896 B: GEMM1 partials, then logits in lgp[0]
    __shared__ uint32_t A_ldsw[K_ * 20];   //  2560 B: A^T bf16 [k][n], row stride 40 u16
    __shared__ float4   x2tmp[32][8];      //  4096 B
    __shared__ float    mxs[32], invs[32];
    __shared__ float    scs[K_], c2s[K_];
    __shared__ float    c2tmp[K_][9];

    unsigned short* xsTs  = (unsigned short*)xsTw;
    unsigned short* A_lds = (unsigned short*)A_ldsw;

    const int tid = threadIdx.x;
    const int l   = tid & 63;
    const int w   = __builtin_amdgcn_readfirstlane(tid >> 6);  // wave id 0..3
    const int lc  = l & 31;   // MFMA: row/col lane index
    const int nh  = l >> 5;   // MFMA: k-dim half selector
    const int b     = blockIdx.x >> 6;
    const int chunk = blockIdx.x & 63;     // 64 chunks of 256 n per batch

    // ---- pre-loop: scale + ||c_k||^2 (fp32) ----
    {
        int k = tid >> 3, dg = tid & 7;
        const float* cr = Cg + k * D_ + dg * 64;
        float s2 = 0.f;
#pragma unroll
        for (int i = 0; i < 16; ++i) {
            float4 v = *(const float4*)(cr + i * 4);
            s2 += v.x * v.x + v.y * v.y + v.z * v.z + v.w * v.w;
        }
        c2tmp[k][dg] = s2;
        if (tid < K_) scs[tid] = scale[tid];
    }
    __syncthreads();
    if (tid < K_) {
        float s = 0.f;
#pragma unroll
        for (int dg = 0; dg < 8; ++dg) s += c2tmp[tid][dg];
        c2s[tid] = s;
    }

    // ---- preload C fragments (GEMM1 B-operand), bf16, per-wave d-steps ----
    // B-frag layout 32x32x16: B[kdim = 8*(lane/32)+j][col = lane%32] = C[col][d]
    F8 cfr[8];
#pragma unroll
    for (int ss = 0; ss < 8; ++ss) {
        int d0 = (8 * w + ss) * 16 + nh * 8;
        const float* cp = Cg + lc * D_ + d0;
        float4 a  = *(const float4*)(cp);
        float4 bq = *(const float4*)(cp + 4);
        cfr[ss].u[0] = bfpack2(a.x, a.y);
        cfr[ss].u[1] = bfpack2(a.z, a.w);
        cfr[ss].u[2] = bfpack2(bq.x, bq.y);
        cfr[ss].u[3] = bfpack2(bq.z, bq.w);
    }

    f32x16 eacc[4];
#pragma unroll
    for (int ti = 0; ti < 4; ++ti)
#pragma unroll
        for (int r = 0; r < 16; ++r) eacc[ti][r] = 0.f;
    float aSumReg = 0.f;

    const int o  = tid >> 3;  // staging: d-line group 0..31
    const int nq = tid & 7;   // staging: n-quad
    const size_t xbase = (size_t)b * D_ * N_ + (size_t)chunk * 256;

    for (int t = 0; t < 8; ++t) {
        __syncthreads();  // previous tile's GEMM2 done -> xsT reusable

        // ---- stage: global fp32 [d][n] -> bf16 LDS + fp32 x2 partials ----
        {
            const float* Xp = X + xbase + t * 32 + nq * 4;
            float4 x2a; x2a.x = x2a.y = x2a.z = x2a.w = 0.f;
#pragma unroll
            for (int r = 0; r < 16; ++r) {
                int d = o + 32 * r;
                float4 v = *(const float4*)(Xp + (size_t)d * N_);
                x2a.x += v.x * v.x; x2a.y += v.y * v.y;
                x2a.z += v.z * v.z; x2a.w += v.w * v.w;
                uint2 p;
                p.x = bfpack2(v.x, v.y);
                p.y = bfpack2(v.z, v.w);
                *(uint2*)&xsTw[d * 20 + nq * 2] = p;
            }
            x2tmp[o][nq] = x2a;
        }
        __syncthreads();  // B1: tile + x2 partials visible

        // ---- GEMM1: logits[n][k] += X[n][d] * C[k][d], steps 8w..8w+8 ----
        // A-frag 32x32x16: A[m=lane%32][kdim=8*(lane/32)+j] = X[n=m][d]
        f32x16 lacc;
#pragma unroll
        for (int r = 0; r < 16; ++r) lacc[r] = 0.f;
#pragma unroll
        for (int ss = 0; ss < 8; ++ss) {
            int d0 = (8 * w + ss) * 16 + nh * 8;
            F8 af;
#pragma unroll
            for (int j = 0; j < 8; ++j)
                af.s[j] = xsTs[(d0 + j) * 40 + lc];
            lacc = __builtin_amdgcn_mfma_f32_32x32x16_bf16(af.v, cfr[ss].v, lacc, 0, 0, 0);
        }
        // D: col = lane&31 (=k), row = (reg&3)+8*(reg>>2)+4*(lane>>5) (=n)
#pragma unroll
        for (int r = 0; r < 16; ++r)
            lgp[w][(r & 3) + 8 * (r >> 2) + 4 * nh][lc] = lacc[r];
        __syncthreads();  // B2: partials ready

        // ---- softmax stage 1 (wave 0, lane = n) ----
        if (w == 0 && l < 32) {
            int n = l;
            float x2v = 0.f;
            const float* xf = (const float*)x2tmp;
#pragma unroll
            for (int oo = 0; oo < 32; ++oo) x2v += xf[oo * 32 + n];
            float lg[K_];
            float m = -3.0e38f;
#pragma unroll
            for (int k = 0; k < K_; ++k) {
                float xc = lgp[0][n][k] + lgp[1][n][k] + lgp[2][n][k] + lgp[3][n][k];
                float sl = scs[k] * (x2v - 2.f * xc + c2s[k]);
                lg[k] = sl;
                m = fmaxf(m, sl);
            }
            float s = 0.f;
#pragma unroll
            for (int k = 0; k < K_; ++k) s += __expf(lg[k] - m);
            mxs[n] = m;
            invs[n] = 1.f / s;
#pragma unroll
            for (int k = 0; k < K_; ++k) lgp[0][n][k] = lg[k];
        }
        __syncthreads();  // B3: mx/inv/logits ready

        // ---- softmax stage 2 (wave 0): A -> bf16 A_lds[k][n] ----
        if (w == 0) {
            int k = lc;
#pragma unroll
            for (int i = 0; i < 16; i += 2) {
                int n = nh * 16 + i;
                float e0 = __expf(lgp[0][n][k]     - mxs[n])     * invs[n];
                float e1 = __expf(lgp[0][n + 1][k] - mxs[n + 1]) * invs[n + 1];
                aSumReg += e0 + e1;
                A_ldsw[k * 20 + (n >> 1)] = bfpack2(e0, e1);
            }
        }
        __syncthreads();  // B4: A ready

        // ---- GEMM2: E[k][d] += A^T[k][n] * X[n][d] ----
        // A-frag: A[m=k=lane%32][kdim=n]; B-frag: B[kdim=n][col=d=lane%32]
#pragma unroll
        for (int ti = 0; ti < 4; ++ti) {
            int dcol = (4 * w + ti) * 32 + lc;
#pragma unroll
            for (int ns = 0; ns < 2; ++ns) {
                F8 af, bf;
                af.q = *(const uint4*)&A_lds[lc * 40 + ns * 16 + nh * 8];
                bf.q = *(const uint4*)&xsTs[dcol * 40 + ns * 16 + nh * 8];
                eacc[ti] = __builtin_amdgcn_mfma_f32_32x32x16_bf16(af.v, bf.v, eacc[ti], 0, 0, 0);
            }
        }
    }

    // ---- finalize: global atomic reduction of E partials ----
    float* accB = acc + (size_t)b * (K_ * D_);
#pragma unroll
    for (int ti = 0; ti < 4; ++ti) {
        int d = (4 * w + ti) * 32 + lc;
#pragma unroll
        for (int r = 0; r < 16; ++r) {
            int k = (r & 3) + 8 * (r >> 2) + 4 * nh;
            unsafeAtomicAdd(&accB[k * D_ + d], eacc[ti][r]);
        }
    }
    if (w == 0) unsafeAtomicAdd(&aSumAcc[b * K_ + lc], aSumReg);
}

// out[b,k,d] = acc[b,k,d] - aSum[b,k] * C[k,d]
__global__ void finish_kernel(const float* __restrict__ acc,
                              const float* __restrict__ aSumAcc,
                              const float* __restrict__ Cg,
                              float* __restrict__ out)
{
    int idx = blockIdx.x * 256 + threadIdx.x;
    int kd = idx & (K_ * D_ - 1);
    int b  = idx >> 14;
    int k  = kd >> 9;
    out[idx] = acc[idx] - aSumAcc[(b << 5) + k] * Cg[kd];
}

extern "C" void kernel_launch(void* const* d_in, const int* in_sizes, int n_in,
                              void* d_out, int out_size, void* d_ws, size_t ws_size,
                              hipStream_t stream)
{
    const float* X  = (const float*)d_in[0];
    const float* C  = (const float*)d_in[1];
    const float* sc = (const float*)d_in[2];
    float* out = (float*)d_out;

    float* acc     = (float*)d_ws;          // B*K*D fp32 partial E
    float* aSumAcc = acc + B_ * K_ * D_;    // B*K fp32 sum of A

    hipMemsetAsync(d_ws, 0, (size_t)(B_ * K_ * D_ + B_ * K_) * sizeof(float), stream);
    encode_kernel<<<B_ * 64, 256, 0, stream>>>(X, C, sc, acc, aSumAcc);
    finish_kernel<<<(B_ * K_ * D_) / 256, 256, 0, stream>>>(acc, aSumAcc, C, out);
}

// Round 3
// 385.447 us; speedup vs baseline: 2.3002x; 1.0192x over previous
//
#include <hip/hip_runtime.h>
#include <stdint.h>

#define B_ 8
#define D_ 512
#define N_ 16384
#define K_ 32

typedef __attribute__((ext_vector_type(8))) short short8;
typedef __attribute__((ext_vector_type(16))) float f32x16;

union F8 { short8 v; unsigned short s[8]; uint32_t u[4]; uint4 q; };

// RNE pack of two fp32 -> bf16x2 in one u32
__device__ __forceinline__ uint32_t bfpack2(float lo, float hi) {
    uint32_t a = __float_as_uint(lo);
    uint32_t b = __float_as_uint(hi);
    a += 0x7FFFu + ((a >> 16) & 1u);
    b += 0x7FFFu + ((b >> 16) & 1u);
    return (a >> 16) | (b & 0xFFFF0000u);
}

// Per block: 256 n (8 tiles of 32) x 512 d. X tile in LDS bf16 [d][n],
// rows padded to 40 u16 (16B-aligned b128 frags for GEMM2).
__launch_bounds__(256, 2)
__global__ void encode_kernel(const float* __restrict__ X,
                              const float* __restrict__ Cg,
                              const float* __restrict__ scale,
                              float* __restrict__ part,
                              float* __restrict__ aSumAcc)
{
    __shared__ uint32_t xsTw[D_ * 20];     // 40960 B: X^T tile bf16, row stride 40 u16
    __shared__ float    lgp[4][32][36];    // 18432 B: GEMM1 per-wave d-partials
    __shared__ uint32_t A_ldsw[K_ * 20];   //  2560 B: A bf16 [k][n], row stride 40 u16
    __shared__ float    x2p[4][32];        //   512 B: per-wave x2 partials
    __shared__ float    scs[K_], c2s[K_];
    __shared__ float    c2tmp[K_][9];
    __shared__ float    aSumLds[K_];

    unsigned short* xsTs  = (unsigned short*)xsTw;
    unsigned short* A_lds = (unsigned short*)A_ldsw;

    const int tid = threadIdx.x;
    const int l   = tid & 63;
    const int w   = __builtin_amdgcn_readfirstlane(tid >> 6);  // wave 0..3
    const int lc  = l & 31;   // MFMA row/col lane
    const int nh  = l >> 5;   // MFMA k-dim half
    const int b     = blockIdx.x >> 6;
    const int chunk = blockIdx.x & 63;     // 64 chunks of 256 n per batch

    // ---- pre-loop: scale + ||c_k||^2 (fp32), zero aSumLds ----
    {
        int k = tid >> 3, dg = tid & 7;
        const float* cr = Cg + k * D_ + dg * 64;
        float s2 = 0.f;
#pragma unroll
        for (int i = 0; i < 16; ++i) {
            float4 v = *(const float4*)(cr + i * 4);
            s2 += v.x * v.x + v.y * v.y + v.z * v.z + v.w * v.w;
        }
        c2tmp[k][dg] = s2;
        if (tid < K_) { scs[tid] = scale[tid]; aSumLds[tid] = 0.f; }
    }
    __syncthreads();
    if (tid < K_) {
        float s = 0.f;
#pragma unroll
        for (int dg = 0; dg < 8; ++dg) s += c2tmp[tid][dg];
        c2s[tid] = s;
    }

    // ---- preload C fragments (GEMM1 B-operand), per-wave d-steps ----
    // B-frag 32x32x16: B[kdim = 8*(lane/32)+j][col = lane%32] = C[col][d]
    F8 cfr[8];
#pragma unroll
    for (int ss = 0; ss < 8; ++ss) {
        int d0 = (8 * w + ss) * 16 + nh * 8;
        const float* cp = Cg + lc * D_ + d0;
        float4 a  = *(const float4*)(cp);
        float4 bq = *(const float4*)(cp + 4);
        cfr[ss].u[0] = bfpack2(a.x, a.y);
        cfr[ss].u[1] = bfpack2(a.z, a.w);
        cfr[ss].u[2] = bfpack2(bq.x, bq.y);
        cfr[ss].u[3] = bfpack2(bq.z, bq.w);
    }

    f32x16 eacc[4];
#pragma unroll
    for (int ti = 0; ti < 4; ++ti)
#pragma unroll
        for (int r = 0; r < 16; ++r) eacc[ti][r] = 0.f;
    float aSumReg[4] = {0.f, 0.f, 0.f, 0.f};

    // softmax lane mapping: 8 lanes per n, 4 k per lane
    const int nl  = l >> 3;            // 0..7 -> n = w*8 + nl
    const int kq  = l & 7;             // k0 = 4*kq
    const int smn = w * 8 + nl;
    const int k0  = kq * 4;

    const int o  = tid >> 3;  // staging: d-line 0..31 (per r-step: d = o+32r)
    const int nq = tid & 7;   // staging: n-quad
    const size_t xbase = (size_t)b * D_ * N_ + (size_t)chunk * 256;

    for (int t = 0; t < 8; ++t) {
        __syncthreads();  // B0: previous tile's GEMM2 done -> xsT reusable

        // ---- stage: global fp32 [d][n] -> bf16 LDS + x2 wave partials ----
        {
            const float* Xp = X + xbase + t * 32 + nq * 4;
            float4 x2a; x2a.x = x2a.y = x2a.z = x2a.w = 0.f;
#pragma unroll
            for (int r = 0; r < 16; ++r) {
                int d = o + 32 * r;
                float4 v = *(const float4*)(Xp + (size_t)d * N_);
                x2a.x += v.x * v.x; x2a.y += v.y * v.y;
                x2a.z += v.z * v.z; x2a.w += v.w * v.w;
                uint2 p;
                p.x = bfpack2(v.x, v.y);
                p.y = bfpack2(v.z, v.w);
                *(uint2*)&xsTw[d * 20 + nq * 2] = p;
            }
            // reduce x2 over the wave's 8 d-line groups (lane bits 3..5)
#pragma unroll
            for (int m = 8; m <= 32; m <<= 1) {
                x2a.x += __shfl_xor(x2a.x, m);
                x2a.y += __shfl_xor(x2a.y, m);
                x2a.z += __shfl_xor(x2a.z, m);
                x2a.w += __shfl_xor(x2a.w, m);
            }
            if (l < 8) *(float4*)&x2p[w][nq * 4] = x2a;
        }
        __syncthreads();  // B1: tile + x2 partials visible

        // ---- GEMM1: logits[n][k] d-partials, steps 8w..8w+8 ----
        // A-frag 32x32x16: A[m=lane%32][kdim=8*(lane/32)+j] = X[n=m][d]
        f32x16 lacc;
#pragma unroll
        for (int r = 0; r < 16; ++r) lacc[r] = 0.f;
#pragma unroll
        for (int ss = 0; ss < 8; ++ss) {
            int d0 = (8 * w + ss) * 16 + nh * 8;
            F8 af;
#pragma unroll
            for (int j = 0; j < 8; ++j)
                af.s[j] = xsTs[(d0 + j) * 40 + lc];
            lacc = __builtin_amdgcn_mfma_f32_32x32x16_bf16(af.v, cfr[ss].v, lacc, 0, 0, 0);
        }
        // D: col = lane&31 (=k), row = (reg&3)+8*(reg>>2)+4*(lane>>5) (=n)
#pragma unroll
        for (int r = 0; r < 16; ++r)
            lgp[w][(r & 3) + 8 * (r >> 2) + 4 * nh][lc] = lacc[r];
        __syncthreads();  // B2: partials + x2 ready

        // ---- softmax: all waves, 8 lanes per n, 4 k per lane ----
        {
            float4 xc = *(const float4*)&lgp[0][smn][k0];
            float4 x1 = *(const float4*)&lgp[1][smn][k0];
            float4 x2q = *(const float4*)&lgp[2][smn][k0];
            float4 x3 = *(const float4*)&lgp[3][smn][k0];
            xc.x += x1.x + x2q.x + x3.x;
            xc.y += x1.y + x2q.y + x3.y;
            xc.z += x1.z + x2q.z + x3.z;
            xc.w += x1.w + x2q.w + x3.w;
            float x2v = x2p[0][smn] + x2p[1][smn] + x2p[2][smn] + x2p[3][smn];
            float sl0 = scs[k0]     * (x2v - 2.f * xc.x + c2s[k0]);
            float sl1 = scs[k0 + 1] * (x2v - 2.f * xc.y + c2s[k0 + 1]);
            float sl2 = scs[k0 + 2] * (x2v - 2.f * xc.z + c2s[k0 + 2]);
            float sl3 = scs[k0 + 3] * (x2v - 2.f * xc.w + c2s[k0 + 3]);
            float m = fmaxf(fmaxf(sl0, sl1), fmaxf(sl2, sl3));
#pragma unroll
            for (int mk = 1; mk <= 4; mk <<= 1) m = fmaxf(m, __shfl_xor(m, mk));
            float e0 = __expf(sl0 - m), e1 = __expf(sl1 - m);
            float e2 = __expf(sl2 - m), e3 = __expf(sl3 - m);
            float s = e0 + e1 + e2 + e3;
#pragma unroll
            for (int mk = 1; mk <= 4; mk <<= 1) s += __shfl_xor(s, mk);
            float inv = 1.f / s;
            e0 *= inv; e1 *= inv; e2 *= inv; e3 *= inv;
            aSumReg[0] += e0; aSumReg[1] += e1;
            aSumReg[2] += e2; aSumReg[3] += e3;
            A_lds[(k0)     * 40 + smn] = (unsigned short)(bfpack2(e0, 0.f));
            A_lds[(k0 + 1) * 40 + smn] = (unsigned short)(bfpack2(e1, 0.f));
            A_lds[(k0 + 2) * 40 + smn] = (unsigned short)(bfpack2(e2, 0.f));
            A_lds[(k0 + 3) * 40 + smn] = (unsigned short)(bfpack2(e3, 0.f));
        }
        __syncthreads();  // B3: A ready

        // ---- GEMM2: E[k][d] += A[k][n] * X[n][d] ----
#pragma unroll
        for (int ti = 0; ti < 4; ++ti) {
            int dcol = (4 * w + ti) * 32 + lc;
#pragma unroll
            for (int ns = 0; ns < 2; ++ns) {
                F8 af, bf;
                af.q = *(const uint4*)&A_lds[lc * 40 + ns * 16 + nh * 8];
                bf.q = *(const uint4*)&xsTs[dcol * 40 + ns * 16 + nh * 8];
                eacc[ti] = __builtin_amdgcn_mfma_f32_32x32x16_bf16(af.v, bf.v, eacc[ti], 0, 0, 0);
            }
        }
    }

    // ---- finalize: plain per-block partial stores (no global atomics) ----
    float* pB = part + (size_t)blockIdx.x * (K_ * D_);
#pragma unroll
    for (int ti = 0; ti < 4; ++ti) {
        int d = (4 * w + ti) * 32 + lc;
#pragma unroll
        for (int r = 0; r < 16; ++r) {
            int k = (r & 3) + 8 * (r >> 2) + 4 * nh;
            pB[k * D_ + d] = eacc[ti][r];
        }
    }

    // aSum: butterfly over the wave's n-lanes, then tiny LDS+global atomics
#pragma unroll
    for (int i = 0; i < 4; ++i) {
#pragma unroll
        for (int m = 8; m <= 32; m <<= 1) aSumReg[i] += __shfl_xor(aSumReg[i], m);
    }
    if (l < 8) {
#pragma unroll
        for (int i = 0; i < 4; ++i) unsafeAtomicAdd(&aSumLds[k0 + i], aSumReg[i]);
    }
    __syncthreads();
    if (tid < K_) unsafeAtomicAdd(&aSumAcc[b * K_ + tid], aSumLds[tid]);
}

// out[b,k,d] = sum_c part[b*64+c][k][d] - aSum[b,k] * C[k,d]
__global__ void finish_kernel(const float* __restrict__ part,
                              const float* __restrict__ aSumAcc,
                              const float* __restrict__ Cg,
                              float* __restrict__ out)
{
    int idx = blockIdx.x * 256 + threadIdx.x;
    int kd = idx & (K_ * D_ - 1);
    int b  = idx >> 14;
    int k  = kd >> 9;
    const float* p = part + (size_t)b * 64 * (K_ * D_) + kd;
    float s = 0.f;
#pragma unroll 8
    for (int c = 0; c < 64; ++c) s += p[(size_t)c * (K_ * D_)];
    out[idx] = s - aSumAcc[(b << 5) + k] * Cg[kd];
}

extern "C" void kernel_launch(void* const* d_in, const int* in_sizes, int n_in,
                              void* d_out, int out_size, void* d_ws, size_t ws_size,
                              hipStream_t stream)
{
    const float* X  = (const float*)d_in[0];
    const float* C  = (const float*)d_in[1];
    const float* sc = (const float*)d_in[2];
    float* out = (float*)d_out;

    float* part    = (float*)d_ws;                    // 512 * K * D fp32 partials (32 MB)
    float* aSumAcc = part + (size_t)512 * K_ * D_;    // B*K fp32

    hipMemsetAsync(aSumAcc, 0, B_ * K_ * sizeof(float), stream);
    encode_kernel<<<B_ * 64, 256, 0, stream>>>(X, C, sc, part, aSumAcc);
    finish_kernel<<<(B_ * K_ * D_) / 256, 256, 0, stream>>>(part, aSumAcc, C, out);
}